// Round 7
// baseline (160.573 us; speedup 1.0000x reference)
//
#include <hip/hip_runtime.h>
#include <hip/hip_fp16.h>
#include <math.h>

#define SS 2048
#define DD 512
#define NH 8
#define HD 64

typedef __attribute__((ext_vector_type(8))) short frag_ab;   // 8 fp16
typedef __attribute__((ext_vector_type(4))) float frag_cd;   // 4 fp32

static __device__ inline unsigned int pack_h2(float x, float y) {
    __half2 t = __floats2half2_rn(x, y);   // x -> low half
    return *(unsigned int*)&t;
}

// ---------- wt[n][k] = fp16(Wq[k][n]) : 512x512 pre-transpose ----------
__global__ __launch_bounds__(256) void wt_kernel(const float* __restrict__ w,
                                                 unsigned short* __restrict__ wt) {
    __shared__ float T[64][69];
    const int tid = threadIdx.x;
    const int tk = blockIdx.x, tn = blockIdx.y;
    #pragma unroll
    for (int p = 0; p < 4; ++p) {
        const int r = (tid >> 4) + p * 16;
        const int c4 = (tid & 15) * 4;
        float4 v = *(const float4*)(w + (size_t)(tk * 64 + r) * 512 + tn * 64 + c4);
        T[r][c4] = v.x; T[r][c4 + 1] = v.y; T[r][c4 + 2] = v.z; T[r][c4 + 3] = v.w;
    }
    __syncthreads();
    #pragma unroll
    for (int p = 0; p < 2; ++p) {
        const int rn = (tid >> 3) + p * 32;
        const int ck = (tid & 7) * 8;
        unsigned int o[4];
        #pragma unroll
        for (int j = 0; j < 4; ++j)
            o[j] = pack_h2(T[ck + 2 * j][rn], T[ck + 2 * j + 1][rn]);
        *(uint4*)(wt + (size_t)(tn * 64 + rn) * 512 + tk * 64 + ck) = *(uint4*)o;
    }
}

// ---------- GEMM: q_h = fp16(x @ Wq). M64 x N64 tiles, dbuf A-LDS, B direct from wt ----------
__global__ __launch_bounds__(256, 4) void gemm_kernel(const float* __restrict__ x,
                                                      const unsigned short* __restrict__ wt,
                                                      unsigned short* __restrict__ q) {
    __shared__ __align__(16) unsigned short Ah[2][64 * 72];
    const int tid = threadIdx.x;
    const int lane = tid & 63, wv = tid >> 6;
    const int a = lane & 15, g = lane >> 4;
    const int bm = blockIdx.x, bn = blockIdx.y;

    frag_cd acc[4] = {};
    const int sr  = tid >> 4;
    const int sc4 = (tid & 15) * 4;

    float4 v[4];
    #pragma unroll
    for (int p = 0; p < 4; ++p)
        v[p] = *(const float4*)(x + (size_t)(bm * 64 + sr + p * 16) * 512 + sc4);

    const unsigned short* wp = wt + (size_t)(bn * 64 + wv * 16 + a) * 512 + g * 8;

    for (int it = 0; it < 8; ++it) {
        const int cur = it & 1;
        #pragma unroll
        for (int p = 0; p < 4; ++p) {
            uint2 hh = { pack_h2(v[p].x, v[p].y), pack_h2(v[p].z, v[p].w) };
            *(uint2*)&Ah[cur][(sr + p * 16) * 72 + sc4] = hh;
        }
        __syncthreads();
        if (it < 7) {
            #pragma unroll
            for (int p = 0; p < 4; ++p)
                v[p] = *(const float4*)(x + (size_t)(bm * 64 + sr + p * 16) * 512 + (it + 1) * 64 + sc4);
        }
        #pragma unroll
        for (int kh = 0; kh < 2; ++kh) {
            const frag_ab bf = *(const frag_ab*)(wp + it * 64 + kh * 32);
            #pragma unroll
            for (int mt = 0; mt < 4; ++mt) {
                const frag_ab af = *(const frag_ab*)&Ah[cur][(mt * 16 + a) * 72 + kh * 32 + g * 8];
                acc[mt] = __builtin_amdgcn_mfma_f32_16x16x32_f16(af, bf, acc[mt], 0, 0, 0);
            }
        }
    }
    #pragma unroll
    for (int mt = 0; mt < 4; ++mt)
        #pragma unroll
        for (int r = 0; r < 4; ++r) {
            const int m = bm * 64 + mt * 16 + g * 4 + r;
            const int n = bn * 64 + wv * 16 + a;
            __half hv = __float2half_rn(acc[mt][r]);
            q[(size_t)m * 512 + n] = *(unsigned short*)&hv;
        }
}

// ---------- Flash attention: f16 MFMA, 64 q/wave, 2-wave blocks, unsplit ----------
// No-max softmax: p = e^(s-8) via exp2; bounded scores make this exact enough in fp32,
// normalization by l at the end. K,V,P each read from LDS exactly once per wave-iter.
// Bank audit: Kt/Pq stride 72 (all their access classes floor-rate); Vt stride 88
// (transposed uint4 writes land 8 lanes/bank-group = floor; 72 would be 2x floor).
__global__ __launch_bounds__(128, 2) void attn_kernel(const __half* __restrict__ qg,
                                                      float* __restrict__ out) {
    __shared__ __align__(16) unsigned short Kt[64 * 72];      // [key][f]
    __shared__ __align__(16) unsigned short Vt[64 * 88];      // [f][key]
    __shared__ __align__(16) unsigned short Pq[2][64 * 72];   // per-wave [q][key]

    const int tid = threadIdx.x;
    const int lane = tid & 63, wv = tid >> 6;
    const int a = lane & 15, g = lane >> 4;
    const int bid = blockIdx.x;       // 512 = 16(qt) * 8(h) * 4(b)
    const int qt = bid & 15;
    const int h  = (bid >> 4) & 7;
    const int b  = bid >> 7;

    const unsigned short* qbh = (const unsigned short*)qg + (size_t)b * SS * DD + h * HD;
    const int qrow0 = qt * 128 + wv * 64;

    // Q B-fragments for 4 sub-tiles of 16 q, pre-scaled by 0.125*log2(e)
    frag_ab qf[4][2];
    const __half2 qsc = __float2half2_rn(0.18033688011112042f);
    #pragma unroll
    for (int nt = 0; nt < 4; ++nt)
        #pragma unroll
        for (int kh = 0; kh < 2; ++kh) {
            frag_ab t = *(const frag_ab*)(qbh + (size_t)(qrow0 + nt * 16 + a) * DD + kh * 32 + g * 8);
            __half2* ph = (__half2*)&t;
            #pragma unroll
            for (int i = 0; i < 4; ++i) ph[i] = __hmul2(ph[i], qsc);
            qf[nt][kh] = t;
        }

    frag_cd oacc[4][4] = {};          // [ft][nt]
    float lsum[4] = {0.f, 0.f, 0.f, 0.f};

    // staging map: 128 threads cover 64 keys x 64 features.
    // thread: features f0,f0+1; key rows r0..r0+7 and r0+32..r0+39 (8-row groups keep
    // the Vt transposed writes at the bank floor).
    const int f0 = (tid & 31) * 2;
    const int r0 = ((tid >> 5) & 3) * 8;
    unsigned short* myP = Pq[wv];

    unsigned int d[16];
    #pragma unroll
    for (int k = 0; k < 8; ++k) {
        d[k]     = *(const unsigned int*)(qbh + (size_t)(r0 + k) * DD + f0);
        d[k + 8] = *(const unsigned int*)(qbh + (size_t)(r0 + 32 + k) * DD + f0);
    }

    for (int it = 0; it < 32; ++it) {
        __syncthreads();              // all waves done reading previous tile
        // ---- stage K (key-major) ----
        #pragma unroll
        for (int k = 0; k < 8; ++k) {
            *(unsigned int*)&Kt[(r0 + k) * 72 + f0]      = d[k];
            *(unsigned int*)&Kt[(r0 + 32 + k) * 72 + f0] = d[k + 8];
        }
        // ---- stage V^T (feature-major) ----
        {
            unsigned int vlo[8], vhi[8];
            #pragma unroll
            for (int j = 0; j < 4; ++j) {
                vlo[j]     = (d[2 * j] & 0xFFFFu)     | (d[2 * j + 1] << 16);
                vhi[j]     = (d[2 * j] >> 16)         | (d[2 * j + 1] & 0xFFFF0000u);
                vlo[j + 4] = (d[8 + 2 * j] & 0xFFFFu) | (d[8 + 2 * j + 1] << 16);
                vhi[j + 4] = (d[8 + 2 * j] >> 16)     | (d[8 + 2 * j + 1] & 0xFFFF0000u);
            }
            *(uint4*)&Vt[f0 * 88 + r0]            = *(uint4*)&vlo[0];
            *(uint4*)&Vt[f0 * 88 + 32 + r0]       = *(uint4*)&vlo[4];
            *(uint4*)&Vt[(f0 + 1) * 88 + r0]      = *(uint4*)&vhi[0];
            *(uint4*)&Vt[(f0 + 1) * 88 + 32 + r0] = *(uint4*)&vhi[4];
        }
        __syncthreads();              // staged tile visible

        if (it + 1 < 32) {            // prefetch next tile (overlaps compute)
            const int kb = (it + 1) * 64;
            #pragma unroll
            for (int k = 0; k < 8; ++k) {
                d[k]     = *(const unsigned int*)(qbh + (size_t)(kb + r0 + k) * DD + f0);
                d[k + 8] = *(const unsigned int*)(qbh + (size_t)(kb + r0 + 32 + k) * DD + f0);
            }
        }

        // ---- S^T = K . Q^T, exp, stage P (kt outer keeps st pressure at 1 frag) ----
        #pragma unroll
        for (int kt = 0; kt < 4; ++kt) {
            const frag_ab ka0 = *(const frag_ab*)&Kt[(kt * 16 + a) * 72 + g * 8];
            const frag_ab ka1 = *(const frag_ab*)&Kt[(kt * 16 + a) * 72 + 32 + g * 8];
            #pragma unroll
            for (int nt = 0; nt < 4; ++nt) {
                frag_cd c = {};
                c = __builtin_amdgcn_mfma_f32_16x16x32_f16(ka0, qf[nt][0], c, 0, 0, 0);
                c = __builtin_amdgcn_mfma_f32_16x16x32_f16(ka1, qf[nt][1], c, 0, 0, 0);
                const float p0 = __builtin_amdgcn_exp2f(c[0] - 11.541560327111707f);
                const float p1 = __builtin_amdgcn_exp2f(c[1] - 11.541560327111707f);
                const float p2 = __builtin_amdgcn_exp2f(c[2] - 11.541560327111707f);
                const float p3 = __builtin_amdgcn_exp2f(c[3] - 11.541560327111707f);
                lsum[nt] += (p0 + p1) + (p2 + p3);
                uint2 pw = { pack_h2(p0, p1), pack_h2(p2, p3) };
                *(uint2*)&myP[(nt * 16 + a) * 72 + kt * 16 + g * 4] = pw;  // wave-private
            }
        }
        // ---- O^T += V^T . P^T ----
        #pragma unroll
        for (int kh = 0; kh < 2; ++kh) {
            frag_ab va[4], pb[4];
            #pragma unroll
            for (int ft = 0; ft < 4; ++ft)
                va[ft] = *(const frag_ab*)&Vt[(ft * 16 + a) * 88 + kh * 32 + g * 8];
            #pragma unroll
            for (int nt = 0; nt < 4; ++nt)
                pb[nt] = *(const frag_ab*)&myP[(nt * 16 + a) * 72 + kh * 32 + g * 8];
            #pragma unroll
            for (int ft = 0; ft < 4; ++ft)
                #pragma unroll
                for (int nt = 0; nt < 4; ++nt)
                    oacc[ft][nt] = __builtin_amdgcn_mfma_f32_16x16x32_f16(va[ft], pb[nt], oacc[ft][nt], 0, 0, 0);
        }
    }

    #pragma unroll
    for (int nt = 0; nt < 4; ++nt) {
        float l = lsum[nt];
        l += __shfl_xor(l, 16, 64);
        l += __shfl_xor(l, 32, 64);
        const float inv = 1.f / l;
        float* op = out + ((size_t)b * SS + qrow0 + nt * 16 + a) * DD + h * HD;
        #pragma unroll
        for (int ft = 0; ft < 4; ++ft) {
            float4 vv = { oacc[ft][nt][0] * inv, oacc[ft][nt][1] * inv,
                          oacc[ft][nt][2] * inv, oacc[ft][nt][3] * inv };
            *(float4*)(op + ft * 16 + g * 4) = vv;
        }
    }
}

extern "C" void kernel_launch(void* const* d_in, const int* in_sizes, int n_in,
                              void* d_out, int out_size, void* d_ws, size_t ws_size,
                              hipStream_t stream) {
    const float* x  = (const float*)d_in[0];
    const float* wq = (const float*)d_in[1];
    float* out = (float*)d_out;

    char* ws = (char*)d_ws;
    unsigned short* q_h = (unsigned short*)ws;                 // 8 MB
    unsigned short* wt  = (unsigned short*)(ws + 8388608u);    // 512 KB

    dim3 tgrid(8, 8);
    wt_kernel<<<tgrid, 256, 0, stream>>>(wq, wt);
    dim3 ggrid(128, 8);
    gemm_kernel<<<ggrid, 256, 0, stream>>>(x, wt, q_h);
    attn_kernel<<<512, 128, 0, stream>>>((const __half*)q_h, out);
}

// Round 8
// 156.600 us; speedup vs baseline: 1.0254x; 1.0254x over previous
//
#include <hip/hip_runtime.h>
#include <hip/hip_fp16.h>
#include <math.h>

#define SS 2048
#define DD 512
#define NH 8
#define HD 64

typedef __attribute__((ext_vector_type(8))) short frag_ab;   // 8 fp16
typedef __attribute__((ext_vector_type(4))) float frag_cd;   // 4 fp32

static __device__ inline unsigned int pack_h2(float x, float y) {
    __half2 t = __floats2half2_rn(x, y);   // x -> low half
    return *(unsigned int*)&t;
}

// ---------- wt[n][k] = fp16(Wq[k][n]) : 512x512 pre-transpose ----------
__global__ __launch_bounds__(256) void wt_kernel(const float* __restrict__ w,
                                                 unsigned short* __restrict__ wt) {
    __shared__ float T[64][69];
    const int tid = threadIdx.x;
    const int tk = blockIdx.x, tn = blockIdx.y;
    #pragma unroll
    for (int p = 0; p < 4; ++p) {
        const int r = (tid >> 4) + p * 16;
        const int c4 = (tid & 15) * 4;
        float4 v = *(const float4*)(w + (size_t)(tk * 64 + r) * 512 + tn * 64 + c4);
        T[r][c4] = v.x; T[r][c4 + 1] = v.y; T[r][c4 + 2] = v.z; T[r][c4 + 3] = v.w;
    }
    __syncthreads();
    #pragma unroll
    for (int p = 0; p < 2; ++p) {
        const int rn = (tid >> 3) + p * 32;
        const int ck = (tid & 7) * 8;
        unsigned int o[4];
        #pragma unroll
        for (int j = 0; j < 4; ++j)
            o[j] = pack_h2(T[ck + 2 * j][rn], T[ck + 2 * j + 1][rn]);
        *(uint4*)(wt + (size_t)(tn * 64 + rn) * 512 + tk * 64 + ck) = *(uint4*)o;
    }
}

// ---------- GEMM: q_h = fp16(x @ Wq). M64 x N64 tiles, dbuf A-LDS, B direct from wt ----------
__global__ __launch_bounds__(256, 4) void gemm_kernel(const float* __restrict__ x,
                                                      const unsigned short* __restrict__ wt,
                                                      unsigned short* __restrict__ q) {
    __shared__ __align__(16) unsigned short Ah[2][64 * 72];
    const int tid = threadIdx.x;
    const int lane = tid & 63, wv = tid >> 6;
    const int a = lane & 15, g = lane >> 4;
    const int bm = blockIdx.x, bn = blockIdx.y;

    frag_cd acc[4] = {};
    const int sr  = tid >> 4;
    const int sc4 = (tid & 15) * 4;

    float4 v[4];
    #pragma unroll
    for (int p = 0; p < 4; ++p)
        v[p] = *(const float4*)(x + (size_t)(bm * 64 + sr + p * 16) * 512 + sc4);

    const unsigned short* wp = wt + (size_t)(bn * 64 + wv * 16 + a) * 512 + g * 8;

    for (int it = 0; it < 8; ++it) {
        const int cur = it & 1;
        #pragma unroll
        for (int p = 0; p < 4; ++p) {
            uint2 hh = { pack_h2(v[p].x, v[p].y), pack_h2(v[p].z, v[p].w) };
            *(uint2*)&Ah[cur][(sr + p * 16) * 72 + sc4] = hh;
        }
        __syncthreads();
        if (it < 7) {
            #pragma unroll
            for (int p = 0; p < 4; ++p)
                v[p] = *(const float4*)(x + (size_t)(bm * 64 + sr + p * 16) * 512 + (it + 1) * 64 + sc4);
        }
        #pragma unroll
        for (int kh = 0; kh < 2; ++kh) {
            const frag_ab bf = *(const frag_ab*)(wp + it * 64 + kh * 32);
            #pragma unroll
            for (int mt = 0; mt < 4; ++mt) {
                const frag_ab af = *(const frag_ab*)&Ah[cur][(mt * 16 + a) * 72 + kh * 32 + g * 8];
                acc[mt] = __builtin_amdgcn_mfma_f32_16x16x32_f16(af, bf, acc[mt], 0, 0, 0);
            }
        }
    }
    #pragma unroll
    for (int mt = 0; mt < 4; ++mt)
        #pragma unroll
        for (int r = 0; r < 4; ++r) {
            const int m = bm * 64 + mt * 16 + g * 4 + r;
            const int n = bn * 64 + wv * 16 + a;
            __half hv = __float2half_rn(acc[mt][r]);
            q[(size_t)m * 512 + n] = *(unsigned short*)&hv;
        }
}

// ---------- Flash attention: 64 q/wave, in-block key-split (4 waves = 2q x 2k) ----------
// No-max softmax: p = e^(s-8); partials over key halves combine exactly through LDS:
// O = (O0+O1)/(l0+l1). Vt stride 68 shorts: transposed uint4 writes AND b128 reads both
// land at the bank floor (68/2=34 ≡ 2 mod 32 spreads rows; 17*4 chunk walk covers all banks).
__global__ __launch_bounds__(256, 2) void attn_kernel(const __half* __restrict__ qg,
                                                      float* __restrict__ out) {
    __shared__ __align__(16) unsigned short Kt[2][64 * 72];   // [kv][key][f]
    __shared__ __align__(16) unsigned short Vt[2][64 * 68];   // [kv][f][key]
    __shared__ __align__(16) unsigned short Pq[4][64 * 72];   // per-wave [q][key]

    const int tid = threadIdx.x;
    const int lane = tid & 63, wv = tid >> 6;
    const int a = lane & 15, g = lane >> 4;
    const int qh = wv & 1;            // q half
    const int kv = wv >> 1;           // key half
    const int bid = blockIdx.x;       // 512 = 16(qt) * 8(h) * 4(b)
    const int qt = bid & 15;
    const int h  = (bid >> 4) & 7;
    const int b  = bid >> 7;

    const unsigned short* qbh = (const unsigned short*)qg + (size_t)b * SS * DD + h * HD;
    const int qrow0 = qt * 128 + qh * 64;

    // Q B-fragments for 4 sub-tiles of 16 q, pre-scaled by 0.125*log2(e)
    frag_ab qf[4][2];
    const __half2 qsc = __float2half2_rn(0.18033688011112042f);
    #pragma unroll
    for (int nt = 0; nt < 4; ++nt)
        #pragma unroll
        for (int kh = 0; kh < 2; ++kh) {
            frag_ab t = *(const frag_ab*)(qbh + (size_t)(qrow0 + nt * 16 + a) * DD + kh * 32 + g * 8);
            __half2* ph = (__half2*)&t;
            #pragma unroll
            for (int i = 0; i < 4; ++i) ph[i] = __hmul2(ph[i], qsc);
            qf[nt][kh] = t;
        }

    frag_cd oacc[4][4] = {};          // [ft][nt]
    float lsum[4] = {0.f, 0.f, 0.f, 0.f};

    // staging: threads 0-127 stage key-half 0's tile, 128-255 stage half 1's.
    const int sel = tid >> 7;
    const int t7  = tid & 127;
    const int f0 = (t7 & 31) * 2;
    const int r0 = ((t7 >> 5) & 3) * 8;
    const int keybase = sel * 1024;
    unsigned short* myP = Pq[wv];
    unsigned short* Ks = Kt[sel];
    unsigned short* Vs = Vt[sel];

    unsigned int d[16];
    #pragma unroll
    for (int k = 0; k < 8; ++k) {
        d[k]     = *(const unsigned int*)(qbh + (size_t)(keybase + r0 + k) * DD + f0);
        d[k + 8] = *(const unsigned int*)(qbh + (size_t)(keybase + r0 + 32 + k) * DD + f0);
    }

    for (int it = 0; it < 16; ++it) {
        __syncthreads();              // all waves done reading previous tiles
        #pragma unroll
        for (int k = 0; k < 8; ++k) { // K key-major
            *(unsigned int*)&Ks[(r0 + k) * 72 + f0]      = d[k];
            *(unsigned int*)&Ks[(r0 + 32 + k) * 72 + f0] = d[k + 8];
        }
        {                             // V^T feature-major
            unsigned int vlo[8], vhi[8];
            #pragma unroll
            for (int j = 0; j < 4; ++j) {
                vlo[j]     = (d[2 * j] & 0xFFFFu)     | (d[2 * j + 1] << 16);
                vhi[j]     = (d[2 * j] >> 16)         | (d[2 * j + 1] & 0xFFFF0000u);
                vlo[j + 4] = (d[8 + 2 * j] & 0xFFFFu) | (d[8 + 2 * j + 1] << 16);
                vhi[j + 4] = (d[8 + 2 * j] >> 16)     | (d[8 + 2 * j + 1] & 0xFFFF0000u);
            }
            *(uint4*)&Vs[f0 * 68 + r0]            = *(uint4*)&vlo[0];
            *(uint4*)&Vs[f0 * 68 + 32 + r0]       = *(uint4*)&vlo[4];
            *(uint4*)&Vs[(f0 + 1) * 68 + r0]      = *(uint4*)&vhi[0];
            *(uint4*)&Vs[(f0 + 1) * 68 + 32 + r0] = *(uint4*)&vhi[4];
        }
        __syncthreads();              // staged tiles visible

        if (it + 1 < 16) {            // prefetch next tile (overlaps compute)
            const int kb = keybase + (it + 1) * 64;
            #pragma unroll
            for (int k = 0; k < 8; ++k) {
                d[k]     = *(const unsigned int*)(qbh + (size_t)(kb + r0 + k) * DD + f0);
                d[k + 8] = *(const unsigned int*)(qbh + (size_t)(kb + r0 + 32 + k) * DD + f0);
            }
        }

        const unsigned short* Kc = Kt[kv];
        const unsigned short* Vc = Vt[kv];

        // ---- S^T = K . Q^T, exp, stage P ----
        #pragma unroll
        for (int kt = 0; kt < 4; ++kt) {
            const frag_ab ka0 = *(const frag_ab*)&Kc[(kt * 16 + a) * 72 + g * 8];
            const frag_ab ka1 = *(const frag_ab*)&Kc[(kt * 16 + a) * 72 + 32 + g * 8];
            #pragma unroll
            for (int nt = 0; nt < 4; ++nt) {
                frag_cd c = {};
                c = __builtin_amdgcn_mfma_f32_16x16x32_f16(ka0, qf[nt][0], c, 0, 0, 0);
                c = __builtin_amdgcn_mfma_f32_16x16x32_f16(ka1, qf[nt][1], c, 0, 0, 0);
                const float p0 = __builtin_amdgcn_exp2f(c[0] - 11.541560327111707f);
                const float p1 = __builtin_amdgcn_exp2f(c[1] - 11.541560327111707f);
                const float p2 = __builtin_amdgcn_exp2f(c[2] - 11.541560327111707f);
                const float p3 = __builtin_amdgcn_exp2f(c[3] - 11.541560327111707f);
                lsum[nt] += (p0 + p1) + (p2 + p3);
                uint2 pw = { pack_h2(p0, p1), pack_h2(p2, p3) };
                *(uint2*)&myP[(nt * 16 + a) * 72 + kt * 16 + g * 4] = pw;  // wave-private
            }
        }
        // ---- O^T += V^T . P^T ----
        #pragma unroll
        for (int kh = 0; kh < 2; ++kh) {
            frag_ab va[4], pb[4];
            #pragma unroll
            for (int ft = 0; ft < 4; ++ft)
                va[ft] = *(const frag_ab*)&Vc[(ft * 16 + a) * 68 + kh * 32 + g * 8];
            #pragma unroll
            for (int nt = 0; nt < 4; ++nt)
                pb[nt] = *(const frag_ab*)&myP[(nt * 16 + a) * 72 + kh * 32 + g * 8];
            #pragma unroll
            for (int ft = 0; ft < 4; ++ft)
                #pragma unroll
                for (int nt = 0; nt < 4; ++nt)
                    oacc[ft][nt] = __builtin_amdgcn_mfma_f32_16x16x32_f16(va[ft], pb[nt], oacc[ft][nt], 0, 0, 0);
        }
    }

    // ---- in-block combine: kv=1 partials -> LDS, kv=0 adds, normalizes, writes ----
    #pragma unroll
    for (int nt = 0; nt < 4; ++nt) {
        lsum[nt] += __shfl_xor(lsum[nt], 16, 64);
        lsum[nt] += __shfl_xor(lsum[nt], 32, 64);
    }
    __syncthreads();                              // tile reads all done; LDS reusable
    float* Obuf = (float*)&Pq[0][0];              // [2][64*65] floats = 33.3 KB
    float* Lbuf = (float*)&Kt[0][0];              // [2][64]
    if (kv == 1) {
        #pragma unroll
        for (int ft = 0; ft < 4; ++ft)
            #pragma unroll
            for (int nt = 0; nt < 4; ++nt)
                #pragma unroll
                for (int r = 0; r < 4; ++r)
                    Obuf[qh * 4160 + (ft * 16 + g * 4 + r) * 65 + nt * 16 + a] = oacc[ft][nt][r];
        if (g == 0)
            #pragma unroll
            for (int nt = 0; nt < 4; ++nt)
                Lbuf[qh * 64 + nt * 16 + a] = lsum[nt];
    }
    __syncthreads();
    if (kv == 0) {
        #pragma unroll
        for (int nt = 0; nt < 4; ++nt) {
            const float inv = 1.f / (lsum[nt] + Lbuf[qh * 64 + nt * 16 + a]);
            float* op = out + ((size_t)b * SS + qrow0 + nt * 16 + a) * DD + h * HD;
            #pragma unroll
            for (int ft = 0; ft < 4; ++ft) {
                const int fb = ft * 16 + g * 4;
                float4 vv = {
                    (oacc[ft][nt][0] + Obuf[qh * 4160 + (fb + 0) * 65 + nt * 16 + a]) * inv,
                    (oacc[ft][nt][1] + Obuf[qh * 4160 + (fb + 1) * 65 + nt * 16 + a]) * inv,
                    (oacc[ft][nt][2] + Obuf[qh * 4160 + (fb + 2) * 65 + nt * 16 + a]) * inv,
                    (oacc[ft][nt][3] + Obuf[qh * 4160 + (fb + 3) * 65 + nt * 16 + a]) * inv };
                *(float4*)(op + fb) = vv;
            }
        }
    }
}

extern "C" void kernel_launch(void* const* d_in, const int* in_sizes, int n_in,
                              void* d_out, int out_size, void* d_ws, size_t ws_size,
                              hipStream_t stream) {
    const float* x  = (const float*)d_in[0];
    const float* wq = (const float*)d_in[1];
    float* out = (float*)d_out;

    char* ws = (char*)d_ws;
    unsigned short* q_h = (unsigned short*)ws;                 // 8 MB
    unsigned short* wt  = (unsigned short*)(ws + 8388608u);    // 512 KB

    dim3 tgrid(8, 8);
    wt_kernel<<<tgrid, 256, 0, stream>>>(wq, wt);
    dim3 ggrid(128, 8);
    gemm_kernel<<<ggrid, 256, 0, stream>>>(x, wt, q_h);
    attn_kernel<<<512, 256, 0, stream>>>((const __half*)q_h, out);
}

// Round 9
// 127.844 us; speedup vs baseline: 1.2560x; 1.2249x over previous
//
#include <hip/hip_runtime.h>
#include <hip/hip_fp16.h>
#include <math.h>

#define SS 2048
#define DD 512
#define NH 8
#define HD 64

typedef __attribute__((ext_vector_type(8))) short frag_ab;   // 8 fp16
typedef __attribute__((ext_vector_type(4))) float frag_cd;   // 4 fp32

static __device__ inline unsigned int pack_h2(float x, float y) {
    __half2 t = __floats2half2_rn(x, y);   // x -> low half
    return *(unsigned int*)&t;
}

// ---------- GEMM: q_h = fp16(x @ Wq); B transposed in-register during staging ----------
// M64 x N64 tiles, grid (128,8) = 1024 blocks, 36.9 KB LDS -> 4 blocks/CU = 16 waves/CU.
__global__ __launch_bounds__(256, 4) void gemm_kernel(const float* __restrict__ x,
                                                      const float* __restrict__ w,
                                                      unsigned short* __restrict__ q) {
    __shared__ __align__(16) unsigned short Ah[2][64 * 72];  // [m][k]
    __shared__ __align__(16) unsigned short Bt[2][64 * 72];  // [n][k] (transposed in staging)
    const int tid = threadIdx.x;
    const int lane = tid & 63, wv = tid >> 6;
    const int a = lane & 15, g = lane >> 4;
    const int bm = blockIdx.x, bn = blockIdx.y;

    frag_cd acc[4] = {};
    // A staging: 16 rows x (16 lanes * 4 floats)
    const int asr = tid >> 4;
    const int ac4 = (tid & 15) * 4;
    // B staging: 2 n-cols x 8 k-rows per thread (transpose pattern)
    const int bnn = (tid & 31) * 2;
    const int bkk = (tid >> 5) * 8;

    float4 av[4];
    float2 bv[8];
    #pragma unroll
    for (int p = 0; p < 4; ++p)
        av[p] = *(const float4*)(x + (size_t)(bm * 64 + asr + p * 16) * 512 + ac4);
    #pragma unroll
    for (int j = 0; j < 8; ++j)
        bv[j] = *(const float2*)(w + (size_t)(bkk + j) * 512 + bn * 64 + bnn);

    for (int it = 0; it < 8; ++it) {
        const int cur = it & 1;
        #pragma unroll
        for (int p = 0; p < 4; ++p) {
            uint2 hh = { pack_h2(av[p].x, av[p].y), pack_h2(av[p].z, av[p].w) };
            *(uint2*)&Ah[cur][(asr + p * 16) * 72 + ac4] = hh;
        }
        {
            unsigned int t0[4], t1[4];
            #pragma unroll
            for (int j = 0; j < 4; ++j) {
                t0[j] = pack_h2(bv[2 * j].x, bv[2 * j + 1].x);
                t1[j] = pack_h2(bv[2 * j].y, bv[2 * j + 1].y);
            }
            *(uint4*)&Bt[cur][bnn * 72 + bkk]       = *(uint4*)t0;
            *(uint4*)&Bt[cur][(bnn + 1) * 72 + bkk] = *(uint4*)t1;
        }
        __syncthreads();
        if (it < 7) {
            const int k0 = (it + 1) * 64;
            #pragma unroll
            for (int p = 0; p < 4; ++p)
                av[p] = *(const float4*)(x + (size_t)(bm * 64 + asr + p * 16) * 512 + k0 + ac4);
            #pragma unroll
            for (int j = 0; j < 8; ++j)
                bv[j] = *(const float2*)(w + (size_t)(k0 + bkk + j) * 512 + bn * 64 + bnn);
        }
        #pragma unroll
        for (int kh = 0; kh < 2; ++kh) {
            const frag_ab bf = *(const frag_ab*)&Bt[cur][(wv * 16 + a) * 72 + kh * 32 + g * 8];
            #pragma unroll
            for (int mt = 0; mt < 4; ++mt) {
                const frag_ab af = *(const frag_ab*)&Ah[cur][(mt * 16 + a) * 72 + kh * 32 + g * 8];
                acc[mt] = __builtin_amdgcn_mfma_f32_16x16x32_f16(af, bf, acc[mt], 0, 0, 0);
            }
        }
    }
    #pragma unroll
    for (int mt = 0; mt < 4; ++mt)
        #pragma unroll
        for (int r = 0; r < 4; ++r) {
            const int m = bm * 64 + mt * 16 + g * 4 + r;
            const int n = bn * 64 + wv * 16 + a;
            __half hv = __float2half_rn(acc[mt][r]);
            q[(size_t)m * 512 + n] = *(unsigned short*)&hv;
        }
}

// ---------- Flash attention: 8 waves = 4 q-quarters (32q) x 2 key-halves; in-block combine ----
// No-max softmax: p = e^(s-8); key-half partials combine exactly: O=(O0+O1)/(l0+l1).
// All LDS strides 72 shorts: every access class (K/V/P reads+writes) is quad-uniform
// (quad = a+g+4kh mod 8) -> bank floor.
__global__ __launch_bounds__(512, 4) void attn_kernel(const __half* __restrict__ qg,
                                                      float* __restrict__ out) {
    __shared__ __align__(16) unsigned short Kt[2][64 * 72];   // [kv][key][f]   18.4 KB
    __shared__ __align__(16) unsigned short Vt[2][64 * 72];   // [kv][f][key]   18.4 KB
    __shared__ __align__(16) unsigned short Pq[8][32 * 72];   // per-wave [q][key] 36.9 KB

    const int tid = threadIdx.x;
    const int lane = tid & 63, wv = tid >> 6;
    const int a = lane & 15, g = lane >> 4;
    const int qq = wv & 3;            // q quarter (32 q)
    const int kv = wv >> 2;           // key half (1024 keys)
    const int bid = blockIdx.x;       // 512 = 16(qt) * 8(h) * 4(b)
    const int qt = bid & 15;
    const int h  = (bid >> 4) & 7;
    const int b  = bid >> 7;

    const unsigned short* qbh = (const unsigned short*)qg + (size_t)b * SS * DD + h * HD;
    const int qrow0 = qt * 128 + qq * 32;

    // Q B-fragments, pre-scaled by 0.125*log2(e)
    frag_ab qf[2][2];
    const __half2 qsc = __float2half2_rn(0.18033688011112042f);
    #pragma unroll
    for (int nt = 0; nt < 2; ++nt)
        #pragma unroll
        for (int kh = 0; kh < 2; ++kh) {
            frag_ab t = *(const frag_ab*)(qbh + (size_t)(qrow0 + nt * 16 + a) * DD + kh * 32 + g * 8);
            __half2* ph = (__half2*)&t;
            #pragma unroll
            for (int i = 0; i < 4; ++i) ph[i] = __hmul2(ph[i], qsc);
            qf[nt][kh] = t;
        }

    frag_cd oacc[4][2] = {};          // [ft][nt]
    float lsum[2] = {0.f, 0.f};

    // staging: threads 0-255 stage key-half 0, 256-511 half 1 (sel == this wave's kv).
    const int t8 = tid & 255;
    const int f0 = (t8 & 31) * 2;
    const int r0 = (t8 >> 5) * 8;     // 8 groups x 8 rows = 64 keys
    const int keybase = (tid >> 8) * 1024;
    unsigned short* Ks = Kt[tid >> 8];
    unsigned short* Vs = Vt[tid >> 8];
    unsigned short* myP = Pq[wv];

    unsigned int d[8];
    #pragma unroll
    for (int k = 0; k < 8; ++k)
        d[k] = *(const unsigned int*)(qbh + (size_t)(keybase + r0 + k) * DD + f0);

    for (int it = 0; it < 16; ++it) {
        __syncthreads();              // all waves done reading previous tiles
        #pragma unroll
        for (int k = 0; k < 8; ++k)   // K key-major
            *(unsigned int*)&Ks[(r0 + k) * 72 + f0] = d[k];
        {                             // V^T feature-major (in-register transpose)
            unsigned int vlo[4], vhi[4];
            #pragma unroll
            for (int j = 0; j < 4; ++j) {
                vlo[j] = (d[2 * j] & 0xFFFFu) | (d[2 * j + 1] << 16);
                vhi[j] = (d[2 * j] >> 16)     | (d[2 * j + 1] & 0xFFFF0000u);
            }
            *(uint4*)&Vs[f0 * 72 + r0]       = *(uint4*)vlo;
            *(uint4*)&Vs[(f0 + 1) * 72 + r0] = *(uint4*)vhi;
        }
        __syncthreads();              // staged tiles visible

        if (it + 1 < 16) {            // prefetch next tile (overlaps compute)
            const int kb = keybase + (it + 1) * 64;
            #pragma unroll
            for (int k = 0; k < 8; ++k)
                d[k] = *(const unsigned int*)(qbh + (size_t)(kb + r0 + k) * DD + f0);
        }

        const unsigned short* Kc = Kt[kv];
        const unsigned short* Vc = Vt[kv];

        // ---- S^T = K . Q^T, exp, stage P ----
        #pragma unroll
        for (int kt = 0; kt < 4; ++kt) {
            const frag_ab ka0 = *(const frag_ab*)&Kc[(kt * 16 + a) * 72 + g * 8];
            const frag_ab ka1 = *(const frag_ab*)&Kc[(kt * 16 + a) * 72 + 32 + g * 8];
            #pragma unroll
            for (int nt = 0; nt < 2; ++nt) {
                frag_cd c = {};
                c = __builtin_amdgcn_mfma_f32_16x16x32_f16(ka0, qf[nt][0], c, 0, 0, 0);
                c = __builtin_amdgcn_mfma_f32_16x16x32_f16(ka1, qf[nt][1], c, 0, 0, 0);
                const float p0 = __builtin_amdgcn_exp2f(c[0] - 11.541560327111707f);
                const float p1 = __builtin_amdgcn_exp2f(c[1] - 11.541560327111707f);
                const float p2 = __builtin_amdgcn_exp2f(c[2] - 11.541560327111707f);
                const float p3 = __builtin_amdgcn_exp2f(c[3] - 11.541560327111707f);
                lsum[nt] += (p0 + p1) + (p2 + p3);
                uint2 pw = { pack_h2(p0, p1), pack_h2(p2, p3) };
                *(uint2*)&myP[(nt * 16 + a) * 72 + kt * 16 + g * 4] = pw;  // wave-private
            }
        }
        // ---- O^T += V^T . P^T ----
        #pragma unroll
        for (int kh = 0; kh < 2; ++kh) {
            frag_ab va[4], pb[2];
            #pragma unroll
            for (int ft = 0; ft < 4; ++ft)
                va[ft] = *(const frag_ab*)&Vc[(ft * 16 + a) * 72 + kh * 32 + g * 8];
            #pragma unroll
            for (int nt = 0; nt < 2; ++nt)
                pb[nt] = *(const frag_ab*)&myP[(nt * 16 + a) * 72 + kh * 32 + g * 8];
            #pragma unroll
            for (int ft = 0; ft < 4; ++ft)
                #pragma unroll
                for (int nt = 0; nt < 2; ++nt)
                    oacc[ft][nt] = __builtin_amdgcn_mfma_f32_16x16x32_f16(va[ft], pb[nt], oacc[ft][nt], 0, 0, 0);
        }
    }

    // ---- in-block combine: kv=1 -> LDS; kv=0 adds, normalizes, writes ----
    #pragma unroll
    for (int nt = 0; nt < 2; ++nt) {
        lsum[nt] += __shfl_xor(lsum[nt], 16, 64);
        lsum[nt] += __shfl_xor(lsum[nt], 32, 64);
    }
    __syncthreads();                              // all tile/P reads done; LDS reusable
    float* Obuf = (float*)&Pq[0][0];              // [qq][f 64][q 32+1 pad] = 33.8 KB
    float* Lbuf = (float*)&Kt[0][0];              // [qq][q 32]
    if (kv == 1) {
        #pragma unroll
        for (int ft = 0; ft < 4; ++ft)
            #pragma unroll
            for (int nt = 0; nt < 2; ++nt)
                #pragma unroll
                for (int r = 0; r < 4; ++r)
                    Obuf[qq * 2112 + (ft * 16 + g * 4 + r) * 33 + nt * 16 + a] = oacc[ft][nt][r];
        if (g == 0)
            #pragma unroll
            for (int nt = 0; nt < 2; ++nt)
                Lbuf[qq * 32 + nt * 16 + a] = lsum[nt];
    }
    __syncthreads();
    if (kv == 0) {
        #pragma unroll
        for (int nt = 0; nt < 2; ++nt) {
            const float inv = 1.f / (lsum[nt] + Lbuf[qq * 32 + nt * 16 + a]);
            float* op = out + ((size_t)b * SS + qrow0 + nt * 16 + a) * DD + h * HD;
            #pragma unroll
            for (int ft = 0; ft < 4; ++ft) {
                const int fb = ft * 16 + g * 4;
                float4 vv = {
                    (oacc[ft][nt][0] + Obuf[qq * 2112 + (fb + 0) * 33 + nt * 16 + a]) * inv,
                    (oacc[ft][nt][1] + Obuf[qq * 2112 + (fb + 1) * 33 + nt * 16 + a]) * inv,
                    (oacc[ft][nt][2] + Obuf[qq * 2112 + (fb + 2) * 33 + nt * 16 + a]) * inv,
                    (oacc[ft][nt][3] + Obuf[qq * 2112 + (fb + 3) * 33 + nt * 16 + a]) * inv };
                *(float4*)(op + fb) = vv;
            }
        }
    }
}

extern "C" void kernel_launch(void* const* d_in, const int* in_sizes, int n_in,
                              void* d_out, int out_size, void* d_ws, size_t ws_size,
                              hipStream_t stream) {
    const float* x  = (const float*)d_in[0];
    const float* wq = (const float*)d_in[1];
    float* out = (float*)d_out;
    unsigned short* q_h = (unsigned short*)d_ws;   // 8 MB

    dim3 ggrid(128, 8);
    gemm_kernel<<<ggrid, 256, 0, stream>>>(x, wq, q_h);
    attn_kernel<<<512, 512, 0, stream>>>((const __half*)q_h, out);
}